// Round 6
// baseline (76.144 us; speedup 1.0000x reference)
//
#include <hip/hip_runtime.h>

// RippleNetPlus fused — 1 block (256 thr) per batch element. DIM=32, HOP=2, MEM=32.
//
// Round 6: round-4/5 body with plain __launch_bounds__(256).
// A/B conclusion from rounds 2/4/5: ANY min-waves-per-EU hint makes the
// backend under-allocate VGPRs (32-40) and generate 60-90MB of scratch
// spill traffic per dispatch. Plain 256 compiled to VGPR=60 / no spill in
// round 2; this body is leaner (14.8KB LDS, bf16 W quad, 5 barriers/hop).

#define NHOP 2

__device__ __forceinline__ float sigmoid_f(float x){ return 1.0f/(1.0f+__expf(-x)); }
__device__ __forceinline__ float tanh_f(float x){
  float e = __expf(2.0f*x);
  return 1.0f - 2.0f/(e + 1.0f);
}
__device__ __forceinline__ unsigned bf16_rtne(float x){
  unsigned u = __float_as_uint(x);
  return (u + 0x7fffu + ((u >> 16) & 1u)) >> 16;
}

__global__ __launch_bounds__(256) void ripple_fused(
    const int* __restrict__ h_i, const int* __restrict__ R_i, const int* __restrict__ t_i,
    const int* __restrict__ v_i,
    const float* __restrict__ entity_emb, const float* __restrict__ relation_emb,
    const float* __restrict__ agg_w1, const float* __restrict__ agg_b1,
    const float* __restrict__ agg_w2, const float* __restrict__ agg_b2,
    const float* __restrict__ gru_w_ih, const float* __restrict__ gru_w_hh,
    const float* __restrict__ gru_b_ih, const float* __restrict__ gru_b_hh,
    const float* __restrict__ ans_w, const float* __restrict__ ans_b,
    float* __restrict__ out)
{
  __shared__ __align__(16) uint2 s_wq[32*32];      // 8 KB bf16 quad, col o^i
  __shared__ __align__(16) float s_rh [8*32*4];    // 4 KB [g][i]{m0..m3}
  __shared__ __align__(16) float s_vsM[32*2];      // [i]{vs,M}
  __shared__ __align__(16) float s_Z  [32];
  __shared__ __align__(16) float s_opart[8*32];    // 1 KB
  __shared__ __align__(16) float s_M  [32];
  __shared__ __align__(16) float s_gig[192];       // gi[0:96], gh[96:192]

  const int b   = blockIdx.x;
  const int tid = threadIdx.x;
  const int g   = tid >> 5;   // group 0..7
  const int o   = tid & 31;
  const int c   = o & 7;
  const int r_  = o >> 3;
  const bool bb4 = (c & 4) != 0;
  const bool bb2 = (c & 2) != 0;
  const bool bb1 = (c & 1) != 0;

  // ---- init: W quad, coalesced global reads -> bf16 RTNE -> swizzled LDS ----
  #pragma unroll
  for (int k = 0; k < 4; ++k){
    int ii = o;
    int oo = g + 8*k;
    float wa = agg_w1[oo*128       + ii];
    float wb = agg_w1[oo*128 + 32  + ii];
    float wc = agg_w1[oo*128 + 64  + ii];
    float wd = agg_w1[oo*128 + 96  + ii];
    s_wq[ii*32 + (oo ^ ii)] = make_uint2(bf16_rtne(wa) | (bf16_rtne(wb) << 16),
                                         bf16_rtne(wc) | (bf16_rtne(wd) << 16));
  }
  float Mreg = 0.f;
  if (tid < 32){
    float v = entity_emb[(size_t)v_i[b]*32 + o];
    s_vsM[o*2+0] = v; s_vsM[o*2+1] = v; s_M[o] = v;
    Mreg = v;
  }
  __syncthreads();

  const float b1v = agg_b1[o];
  const float w2v = agg_w2[o];

  for (int hop = 0; hop < NHOP; ++hop){
    const int ibase = (b*NHOP + hop)*32;

    // ---- t-row prefetch (latency hides under phase A/B) ----
    float tv[4];
    #pragma unroll
    for (int ml = 0; ml < 4; ++ml)
      tv[ml] = entity_emb[(size_t)t_i[ibase + g*4 + ml]*32 + o];

    // ---- phase A: Rh for this group's 4 memories (coalesced + butterfly) ----
    {
      float rh4[4];
      #pragma unroll
      for (int ml = 0; ml < 4; ++ml){
        int m    = g*4 + ml;
        int ridx = R_i[ibase + m];
        int hidx = h_i[ibase + m];
        const float* Rbase = relation_emb + (size_t)ridx*1024;
        float4 hv = *(const float4*)(entity_emb + (size_t)hidx*32 + c*4);
        float p[8];
        #pragma unroll
        for (int q = 0; q < 8; ++q){
          float4 rv = *(const float4*)(Rbase + q*128 + o*4);
          p[q] = rv.x*hv.x + rv.y*hv.y + rv.z*hv.z + rv.w*hv.w;
        }
        #pragma unroll
        for (int k = 0; k < 4; ++k){
          float send = bb4 ? p[k] : p[k+4];
          float t = __shfl_xor(send, 4);
          p[k] = (bb4 ? p[k+4] : p[k]) + t;
        }
        #pragma unroll
        for (int k = 0; k < 2; ++k){
          float send = bb2 ? p[k] : p[k+2];
          float t = __shfl_xor(send, 2);
          p[k] = (bb2 ? p[k+2] : p[k]) + t;
        }
        {
          float send = bb1 ? p[0] : p[1];
          float t = __shfl_xor(send, 1);
          p[0] = (bb1 ? p[1] : p[0]) + t;
        }
        rh4[ml] = p[0];
      }
      int j = c*4 + r_;   // bijective lane->row
      *(float4*)&s_rh[(g*32 + j)*4] = make_float4(rh4[0],rh4[1],rh4[2],rh4[3]);
    }
    __syncthreads();

    // ---- phase B: hidden + score, 4 memories per group ----
    {
      const float4* rh_p = (const float4*)&s_rh[(g*32)*4];
      float a0=0.f, a1=0.f, a2=0.f, a3=0.f;
      #pragma unroll 8
      for (int i = 0; i < 32; ++i){
        uint2 wd2 = s_wq[i*32 + (o ^ i)];
        float wa = __uint_as_float(wd2.x << 16);
        float wb = __uint_as_float(wd2.x & 0xffff0000u);
        float wc = __uint_as_float(wd2.y << 16);
        float wd = __uint_as_float(wd2.y & 0xffff0000u);
        float2 vm = *(const float2*)&s_vsM[i*2];
        float  cp = vm.x*wa + vm.y*wb;
        float4 rh = rh_p[i];
        a0 += rh.x*cp + fabsf(rh.x-vm.x)*wc + fabsf(rh.x-vm.y)*wd;
        a1 += rh.y*cp + fabsf(rh.y-vm.x)*wc + fabsf(rh.y-vm.y)*wd;
        a2 += rh.z*cp + fabsf(rh.z-vm.x)*wc + fabsf(rh.z-vm.y)*wd;
        a3 += rh.w*cp + fabsf(rh.w-vm.x)*wc + fabsf(rh.w-vm.y)*wd;
      }
      float v4[4];
      v4[0] = tanh_f(a0 + b1v) * w2v;
      v4[1] = tanh_f(a1 + b1v) * w2v;
      v4[2] = tanh_f(a2 + b1v) * w2v;
      v4[3] = tanh_f(a3 + b1v) * w2v;
      // packed butterfly: 4 values over 32 lanes (6 shfl)
      const bool t4 = (o & 16) != 0;
      #pragma unroll
      for (int k = 0; k < 2; ++k){
        float send = t4 ? v4[k] : v4[k+2];
        float t = __shfl_xor(send, 16);
        v4[k] = (t4 ? v4[k+2] : v4[k]) + t;
      }
      const bool t3 = (o & 8) != 0;
      {
        float send = t3 ? v4[0] : v4[1];
        float t = __shfl_xor(send, 8);
        v4[0] = (t3 ? v4[1] : v4[0]) + t;
      }
      v4[0] += __shfl_xor(v4[0], 4);
      v4[0] += __shfl_xor(v4[0], 2);
      v4[0] += __shfl_xor(v4[0], 1);
      if ((o & 7) == 0){
        int ml = ((o >> 4) & 1)*2 + ((o >> 3) & 1);
        s_Z[g*4 + ml] = v4[0];
      }
    }
    __syncthreads();

    // ---- phase C: softmax on all lanes; weighted-t partials ----
    {
      float z  = s_Z[o];
      float mx = z;
      #pragma unroll
      for (int s = 16; s > 0; s >>= 1) mx = fmaxf(mx, __shfl_xor(mx, s));
      float e  = __expf(z - mx);
      float sm = e;
      #pragma unroll
      for (int s = 16; s > 0; s >>= 1) sm += __shfl_xor(sm, s);
      float gval = e / sm;   // lane o holds gate for memory o
      float po = 0.f;
      #pragma unroll
      for (int ml = 0; ml < 4; ++ml)
        po += __shfl(gval, g*4 + ml) * tv[ml];
      s_opart[g*32 + o] = po;
    }
    __syncthreads();

    // ---- phase D: GRU gates, distributed, coalesced b128 weight loads ----
    {
      const int cc = (tid & 7) * 4;
      const int rr = tid >> 3;          // 0..31
      float4 o4 = make_float4(0,0,0,0);
      #pragma unroll
      for (int gg = 0; gg < 8; ++gg){
        float4 t = *(const float4*)&s_opart[gg*32 + cc];
        o4.x += t.x; o4.y += t.y; o4.z += t.z; o4.w += t.w;
      }
      float4 m4 = *(const float4*)&s_M[cc];
      #pragma unroll
      for (int k = 0; k < 3; ++k){
        int row = k*32 + rr;
        float4 wi = *(const float4*)(gru_w_ih + ((size_t)hop*96 + row)*32 + cc);
        float4 wh = *(const float4*)(gru_w_hh + ((size_t)hop*96 + row)*32 + cc);
        float ai = wi.x*o4.x + wi.y*o4.y + wi.z*o4.z + wi.w*o4.w;
        float ah = wh.x*m4.x + wh.y*m4.y + wh.z*m4.z + wh.w*m4.w;
        ai += __shfl_xor(ai,1); ai += __shfl_xor(ai,2); ai += __shfl_xor(ai,4);
        ah += __shfl_xor(ah,1); ah += __shfl_xor(ah,2); ah += __shfl_xor(ah,4);
        if ((tid & 7) == 0){
          s_gig[row]      = ai;
          s_gig[96 + row] = ah;
        }
      }
    }
    __syncthreads();

    // ---- phase E: GRU state update (lanes 0..31), biases from global ----
    if (tid < 32){
      const float* bih = gru_b_ih + hop*96;
      const float* bhh = gru_b_hh + hop*96;
      float ir = s_gig[o]       + bih[o];
      float iz = s_gig[32 + o]  + bih[32 + o];
      float in_= s_gig[64 + o]  + bih[64 + o];
      float hr = s_gig[96 + o]  + bhh[o];
      float hz = s_gig[128 + o] + bhh[32 + o];
      float hn = s_gig[160 + o] + bhh[64 + o];
      float r  = sigmoid_f(ir + hr);
      float zz = sigmoid_f(iz + hz);
      float n  = tanh_f(in_ + r*hn);
      float Mn = (1.f - zz)*n + zz*Mreg;
      Mreg = Mn;
      s_M[o] = Mn;
      s_vsM[o*2+1] = Mn;
    }
    __syncthreads();
  }

  // ---- epilogue: Mw = sigmoid(M @ ans_w.T + ans_b); out = vs . Mw ----
  {
    const int cc = (tid & 7) * 4;
    const int rr = tid >> 3;
    float4 m4 = *(const float4*)&s_M[cc];
    float4 aw = *(const float4*)(ans_w + (size_t)rr*32 + cc);
    float a = aw.x*m4.x + aw.y*m4.y + aw.z*m4.z + aw.w*m4.w;
    a += __shfl_xor(a,1); a += __shfl_xor(a,2); a += __shfl_xor(a,4);
    if ((tid & 7) == 0) s_Z[rr] = sigmoid_f(a + ans_b[rr]);
  }
  __syncthreads();
  if (tid < 32){
    float val = s_vsM[o*2+0] * s_Z[o];
    #pragma unroll
    for (int s = 16; s > 0; s >>= 1) val += __shfl_xor(val, s);
    if (tid == 0) out[b] = val;
  }
}

extern "C" void kernel_launch(void* const* d_in, const int* in_sizes, int n_in,
                              void* d_out, int out_size, void* d_ws, size_t ws_size,
                              hipStream_t stream) {
  const int*   h_i          = (const int*)  d_in[0];
  const int*   R_i          = (const int*)  d_in[1];
  const int*   t_i          = (const int*)  d_in[2];
  const int*   v_i          = (const int*)  d_in[3];
  const float* entity_emb   = (const float*)d_in[4];
  const float* relation_emb = (const float*)d_in[5];
  const float* agg_w1       = (const float*)d_in[6];
  const float* agg_b1       = (const float*)d_in[7];
  const float* agg_w2       = (const float*)d_in[8];
  const float* agg_b2       = (const float*)d_in[9];   // softmax-invariant, dropped
  const float* gru_w_ih     = (const float*)d_in[10];
  const float* gru_w_hh     = (const float*)d_in[11];
  const float* gru_b_ih     = (const float*)d_in[12];
  const float* gru_b_hh     = (const float*)d_in[13];
  const float* ans_w        = (const float*)d_in[14];
  const float* ans_b        = (const float*)d_in[15];
  (void)agg_b2;
  float* outp = (float*)d_out;

  const int batch = in_sizes[3];
  ripple_fused<<<batch, 256, 0, stream>>>(
      h_i, R_i, t_i, v_i, entity_emb, relation_emb,
      agg_w1, agg_b1, agg_w2, agg_b2,
      gru_w_ih, gru_w_hh, gru_b_ih, gru_b_hh,
      ans_w, ans_b, outp);
}

// Round 7
// 60.841 us; speedup vs baseline: 1.2515x; 1.2515x over previous
//
#include <hip/hip_runtime.h>

// RippleNetPlus fused — 1 block (256 thr) per batch element. DIM=32, HOP=2, MEM=32.
//
// Round 7: round-6 body, phase-A ml-loop NOT unrolled (#pragma unroll 1).
// Goal: natural VGPR <= 64 (8 waves/SIMD step) with zero spill. Evidence:
// R2 VGPR60/occ39/71.8 ; R4 spill/occ75/69.0 ; R6 VGPR104/occ20/76.1.
// Occupancy is the dominant term (latency-bound, VALU~50%, HBM~2%); grid
// gives max 8 blocks/CU, LDS 14.8KB not limiting, VGPR is the only knob.
// waves_per_eu hints are toxic (compiler under-allocates + spills 60-90MB).

#define NHOP 2

__device__ __forceinline__ float sigmoid_f(float x){ return 1.0f/(1.0f+__expf(-x)); }
__device__ __forceinline__ float tanh_f(float x){
  float e = __expf(2.0f*x);
  return 1.0f - 2.0f/(e + 1.0f);
}
__device__ __forceinline__ unsigned bf16_rtne(float x){
  unsigned u = __float_as_uint(x);
  return (u + 0x7fffu + ((u >> 16) & 1u)) >> 16;
}

__global__ __launch_bounds__(256) void ripple_fused(
    const int* __restrict__ h_i, const int* __restrict__ R_i, const int* __restrict__ t_i,
    const int* __restrict__ v_i,
    const float* __restrict__ entity_emb, const float* __restrict__ relation_emb,
    const float* __restrict__ agg_w1, const float* __restrict__ agg_b1,
    const float* __restrict__ agg_w2, const float* __restrict__ agg_b2,
    const float* __restrict__ gru_w_ih, const float* __restrict__ gru_w_hh,
    const float* __restrict__ gru_b_ih, const float* __restrict__ gru_b_hh,
    const float* __restrict__ ans_w, const float* __restrict__ ans_b,
    float* __restrict__ out)
{
  __shared__ __align__(16) uint2 s_wq[32*32];      // 8 KB bf16 quad, col o^i
  __shared__ __align__(16) float s_rh [8*32*4];    // 4 KB [g][i]{m0..m3}
  __shared__ __align__(16) float s_vsM[32*2];      // [i]{vs,M}
  __shared__ __align__(16) float s_Z  [32];
  __shared__ __align__(16) float s_opart[8*32];    // 1 KB
  __shared__ __align__(16) float s_M  [32];
  __shared__ __align__(16) float s_gig[192];       // gi[0:96], gh[96:192]

  const int b   = blockIdx.x;
  const int tid = threadIdx.x;
  const int g   = tid >> 5;   // group 0..7
  const int o   = tid & 31;
  const int c   = o & 7;
  const int r_  = o >> 3;
  const bool bb4 = (c & 4) != 0;
  const bool bb2 = (c & 2) != 0;
  const bool bb1 = (c & 1) != 0;

  // ---- init: W quad, coalesced global reads -> bf16 RTNE -> swizzled LDS ----
  #pragma unroll
  for (int k = 0; k < 4; ++k){
    int ii = o;
    int oo = g + 8*k;
    float wa = agg_w1[oo*128       + ii];
    float wb = agg_w1[oo*128 + 32  + ii];
    float wc = agg_w1[oo*128 + 64  + ii];
    float wd = agg_w1[oo*128 + 96  + ii];
    s_wq[ii*32 + (oo ^ ii)] = make_uint2(bf16_rtne(wa) | (bf16_rtne(wb) << 16),
                                         bf16_rtne(wc) | (bf16_rtne(wd) << 16));
  }
  float Mreg = 0.f;
  if (tid < 32){
    float v = entity_emb[(size_t)v_i[b]*32 + o];
    s_vsM[o*2+0] = v; s_vsM[o*2+1] = v; s_M[o] = v;
    Mreg = v;
  }
  __syncthreads();

  const float b1v = agg_b1[o];
  const float w2v = agg_w2[o];

  for (int hop = 0; hop < NHOP; ++hop){
    const int ibase = (b*NHOP + hop)*32;

    // ---- t-row prefetch (latency hides under phase A/B) ----
    float tv[4];
    #pragma unroll
    for (int ml = 0; ml < 4; ++ml)
      tv[ml] = entity_emb[(size_t)t_i[ibase + g*4 + ml]*32 + o];

    // ---- phase A: Rh for this group's 4 memories (coalesced + butterfly) ----
    // unroll 1: keeps ~1 memory's loads in flight -> VGPR <= 64, no spill.
    {
      float rh4[4];
      #pragma unroll 1
      for (int ml = 0; ml < 4; ++ml){
        int m    = g*4 + ml;
        int ridx = R_i[ibase + m];
        int hidx = h_i[ibase + m];
        const float* Rbase = relation_emb + (size_t)ridx*1024;
        float4 hv = *(const float4*)(entity_emb + (size_t)hidx*32 + c*4);
        float p[8];
        #pragma unroll
        for (int q = 0; q < 8; ++q){
          float4 rv = *(const float4*)(Rbase + q*128 + o*4);
          p[q] = rv.x*hv.x + rv.y*hv.y + rv.z*hv.z + rv.w*hv.w;
        }
        #pragma unroll
        for (int k = 0; k < 4; ++k){
          float send = bb4 ? p[k] : p[k+4];
          float t = __shfl_xor(send, 4);
          p[k] = (bb4 ? p[k+4] : p[k]) + t;
        }
        #pragma unroll
        for (int k = 0; k < 2; ++k){
          float send = bb2 ? p[k] : p[k+2];
          float t = __shfl_xor(send, 2);
          p[k] = (bb2 ? p[k+2] : p[k]) + t;
        }
        {
          float send = bb1 ? p[0] : p[1];
          float t = __shfl_xor(send, 1);
          p[0] = (bb1 ? p[1] : p[0]) + t;
        }
        rh4[ml] = p[0];
      }
      int j = c*4 + r_;   // bijective lane->row
      *(float4*)&s_rh[(g*32 + j)*4] = make_float4(rh4[0],rh4[1],rh4[2],rh4[3]);
    }
    __syncthreads();

    // ---- phase B: hidden + score, 4 memories per group ----
    {
      const float4* rh_p = (const float4*)&s_rh[(g*32)*4];
      float a0=0.f, a1=0.f, a2=0.f, a3=0.f;
      #pragma unroll 4
      for (int i = 0; i < 32; ++i){
        uint2 wd2 = s_wq[i*32 + (o ^ i)];
        float wa = __uint_as_float(wd2.x << 16);
        float wb = __uint_as_float(wd2.x & 0xffff0000u);
        float wc = __uint_as_float(wd2.y << 16);
        float wd = __uint_as_float(wd2.y & 0xffff0000u);
        float2 vm = *(const float2*)&s_vsM[i*2];
        float  cp = vm.x*wa + vm.y*wb;
        float4 rh = rh_p[i];
        a0 += rh.x*cp + fabsf(rh.x-vm.x)*wc + fabsf(rh.x-vm.y)*wd;
        a1 += rh.y*cp + fabsf(rh.y-vm.x)*wc + fabsf(rh.y-vm.y)*wd;
        a2 += rh.z*cp + fabsf(rh.z-vm.x)*wc + fabsf(rh.z-vm.y)*wd;
        a3 += rh.w*cp + fabsf(rh.w-vm.x)*wc + fabsf(rh.w-vm.y)*wd;
      }
      float v4[4];
      v4[0] = tanh_f(a0 + b1v) * w2v;
      v4[1] = tanh_f(a1 + b1v) * w2v;
      v4[2] = tanh_f(a2 + b1v) * w2v;
      v4[3] = tanh_f(a3 + b1v) * w2v;
      // packed butterfly: 4 values over 32 lanes (6 shfl)
      const bool t4 = (o & 16) != 0;
      #pragma unroll
      for (int k = 0; k < 2; ++k){
        float send = t4 ? v4[k] : v4[k+2];
        float t = __shfl_xor(send, 16);
        v4[k] = (t4 ? v4[k+2] : v4[k]) + t;
      }
      const bool t3 = (o & 8) != 0;
      {
        float send = t3 ? v4[0] : v4[1];
        float t = __shfl_xor(send, 8);
        v4[0] = (t3 ? v4[1] : v4[0]) + t;
      }
      v4[0] += __shfl_xor(v4[0], 4);
      v4[0] += __shfl_xor(v4[0], 2);
      v4[0] += __shfl_xor(v4[0], 1);
      if ((o & 7) == 0){
        int ml = ((o >> 4) & 1)*2 + ((o >> 3) & 1);
        s_Z[g*4 + ml] = v4[0];
      }
    }
    __syncthreads();

    // ---- phase C: softmax on all lanes; weighted-t partials ----
    {
      float z  = s_Z[o];
      float mx = z;
      #pragma unroll
      for (int s = 16; s > 0; s >>= 1) mx = fmaxf(mx, __shfl_xor(mx, s));
      float e  = __expf(z - mx);
      float sm = e;
      #pragma unroll
      for (int s = 16; s > 0; s >>= 1) sm += __shfl_xor(sm, s);
      float gval = e / sm;   // lane o holds gate for memory o
      float po = 0.f;
      #pragma unroll
      for (int ml = 0; ml < 4; ++ml)
        po += __shfl(gval, g*4 + ml) * tv[ml];
      s_opart[g*32 + o] = po;
    }
    __syncthreads();

    // ---- phase D: GRU gates, distributed, coalesced b128 weight loads ----
    {
      const int cc = (tid & 7) * 4;
      const int rr = tid >> 3;          // 0..31
      float4 o4 = make_float4(0,0,0,0);
      #pragma unroll
      for (int gg = 0; gg < 8; ++gg){
        float4 t = *(const float4*)&s_opart[gg*32 + cc];
        o4.x += t.x; o4.y += t.y; o4.z += t.z; o4.w += t.w;
      }
      float4 m4 = *(const float4*)&s_M[cc];
      #pragma unroll
      for (int k = 0; k < 3; ++k){
        int row = k*32 + rr;
        float4 wi = *(const float4*)(gru_w_ih + ((size_t)hop*96 + row)*32 + cc);
        float4 wh = *(const float4*)(gru_w_hh + ((size_t)hop*96 + row)*32 + cc);
        float ai = wi.x*o4.x + wi.y*o4.y + wi.z*o4.z + wi.w*o4.w;
        float ah = wh.x*m4.x + wh.y*m4.y + wh.z*m4.z + wh.w*m4.w;
        ai += __shfl_xor(ai,1); ai += __shfl_xor(ai,2); ai += __shfl_xor(ai,4);
        ah += __shfl_xor(ah,1); ah += __shfl_xor(ah,2); ah += __shfl_xor(ah,4);
        if ((tid & 7) == 0){
          s_gig[row]      = ai;
          s_gig[96 + row] = ah;
        }
      }
    }
    __syncthreads();

    // ---- phase E: GRU state update (lanes 0..31), biases from global ----
    if (tid < 32){
      const float* bih = gru_b_ih + hop*96;
      const float* bhh = gru_b_hh + hop*96;
      float ir = s_gig[o]       + bih[o];
      float iz = s_gig[32 + o]  + bih[32 + o];
      float in_= s_gig[64 + o]  + bih[64 + o];
      float hr = s_gig[96 + o]  + bhh[o];
      float hz = s_gig[128 + o] + bhh[32 + o];
      float hn = s_gig[160 + o] + bhh[64 + o];
      float r  = sigmoid_f(ir + hr);
      float zz = sigmoid_f(iz + hz);
      float n  = tanh_f(in_ + r*hn);
      float Mn = (1.f - zz)*n + zz*Mreg;
      Mreg = Mn;
      s_M[o] = Mn;
      s_vsM[o*2+1] = Mn;
    }
    __syncthreads();
  }

  // ---- epilogue: Mw = sigmoid(M @ ans_w.T + ans_b); out = vs . Mw ----
  {
    const int cc = (tid & 7) * 4;
    const int rr = tid >> 3;
    float4 m4 = *(const float4*)&s_M[cc];
    float4 aw = *(const float4*)(ans_w + (size_t)rr*32 + cc);
    float a = aw.x*m4.x + aw.y*m4.y + aw.z*m4.z + aw.w*m4.w;
    a += __shfl_xor(a,1); a += __shfl_xor(a,2); a += __shfl_xor(a,4);
    if ((tid & 7) == 0) s_Z[rr] = sigmoid_f(a + ans_b[rr]);
  }
  __syncthreads();
  if (tid < 32){
    float val = s_vsM[o*2+0] * s_Z[o];
    #pragma unroll
    for (int s = 16; s > 0; s >>= 1) val += __shfl_xor(val, s);
    if (tid == 0) out[b] = val;
  }
}

extern "C" void kernel_launch(void* const* d_in, const int* in_sizes, int n_in,
                              void* d_out, int out_size, void* d_ws, size_t ws_size,
                              hipStream_t stream) {
  const int*   h_i          = (const int*)  d_in[0];
  const int*   R_i          = (const int*)  d_in[1];
  const int*   t_i          = (const int*)  d_in[2];
  const int*   v_i          = (const int*)  d_in[3];
  const float* entity_emb   = (const float*)d_in[4];
  const float* relation_emb = (const float*)d_in[5];
  const float* agg_w1       = (const float*)d_in[6];
  const float* agg_b1       = (const float*)d_in[7];
  const float* agg_w2       = (const float*)d_in[8];
  const float* agg_b2       = (const float*)d_in[9];   // softmax-invariant, dropped
  const float* gru_w_ih     = (const float*)d_in[10];
  const float* gru_w_hh     = (const float*)d_in[11];
  const float* gru_b_ih     = (const float*)d_in[12];
  const float* gru_b_hh     = (const float*)d_in[13];
  const float* ans_w        = (const float*)d_in[14];
  const float* ans_b        = (const float*)d_in[15];
  (void)agg_b2;
  float* outp = (float*)d_out;

  const int batch = in_sizes[3];
  ripple_fused<<<batch, 256, 0, stream>>>(
      h_i, R_i, t_i, v_i, entity_emb, relation_emb,
      agg_w1, agg_b1, agg_w2, agg_b2,
      gru_w_ih, gru_w_hh, gru_b_ih, gru_b_hh,
      ans_w, ans_b, outp);
}